// Round 11
// baseline (554.492 us; speedup 1.0000x reference)
//
#include <hip/hip_runtime.h>

#define N_NODES 100000
#define N_EDGES 1600000
#define BN_EPS 1e-5f
#define NB_SCAN 98       // ceil(100000/1024)
#define PART_SZ 12500    // N_NODES / 8 XCD partitions
#define FILL_CHUNKS 1024
#define CHUNK_SZ 1563    // ceil(N_EDGES / FILL_CHUNKS)

// broadcast lane k's value (readlane). Wave-uniform control flow ONLY.
__device__ __forceinline__ float bcast(float v, int k) {
    return __uint_as_float(__builtin_amdgcn_readlane(__float_as_uint(v), k));
}
__device__ __forceinline__ float bf16lo(unsigned int w) {
    return __uint_as_float(w << 16);
}
__device__ __forceinline__ float bf16hi(unsigned int w) {
    return __uint_as_float(w & 0xFFFF0000u);
}
__device__ __forceinline__ unsigned short f2bf(float x) {   // round-nearest-even
    unsigned int u = __float_as_uint(x);
    return (unsigned short)((u + 0x7FFF + ((u >> 16) & 1)) >> 16);
}

// ===========================================================================
// CSR build, XCD-partitioned (R10, proven): grid = FILL_CHUNKS x 8; block b
// scans chunk b>>3, keeps dst in partition (b&7) -> per-XCD L2 owns its
// 1/8 slice of deg/cursor/nbr; scattered stores merge in-L2.
// ===========================================================================
__global__ __launch_bounds__(256) void histogram_xcd_kernel(
    const int* __restrict__ dst, int* __restrict__ deg)
{
    int part  = blockIdx.x & 7;
    int lo = part * PART_SZ, hi = lo + PART_SZ;
    int base  = (blockIdx.x >> 3) * CHUNK_SZ;
    int endE  = min(base + CHUNK_SZ, N_EDGES);
    for (int e = base + threadIdx.x; e < endE; e += 256) {
        int d = dst[e];
        if (d >= lo && d < hi) atomicAdd(&deg[d], 1);
    }
}

__global__ __launch_bounds__(256) void fill_xcd_kernel(
    const int* __restrict__ src, const int* __restrict__ dst,
    int* __restrict__ cursor, int* __restrict__ nbr)
{
    int part  = blockIdx.x & 7;
    int lo = part * PART_SZ, hi = lo + PART_SZ;
    int base  = (blockIdx.x >> 3) * CHUNK_SZ;
    int endE  = min(base + CHUNK_SZ, N_EDGES);
    for (int e = base + threadIdx.x; e < endE; e += 256) {
        int d = dst[e];
        if (d >= lo && d < hi) {
            int p = atomicAdd(&cursor[d], 1);
            nbr[p] = src[e];
        }
    }
}

__global__ __launch_bounds__(1024) void scan1_kernel(
    const int* __restrict__ deg, int* __restrict__ offs, int* __restrict__ bsum)
{
    __shared__ int tmp[1024];
    int gid = blockIdx.x * 1024 + threadIdx.x;
    int v = (gid < N_NODES) ? deg[gid] : 0;
    tmp[threadIdx.x] = v;
    __syncthreads();
    for (int off = 1; off < 1024; off <<= 1) {
        int t = (threadIdx.x >= off) ? tmp[threadIdx.x - off] : 0;
        __syncthreads();
        tmp[threadIdx.x] += t;
        __syncthreads();
    }
    if (gid < N_NODES) offs[gid] = tmp[threadIdx.x] - v;
    if (threadIdx.x == 1023) bsum[blockIdx.x] = tmp[1023];
}

// scan3b: replaces scan2+scan3 — each block redundantly reduces bsum[0..
// blockIdx) (128 parallel loads + LDS tree, ~1 us) to get its base offset.
__global__ __launch_bounds__(1024) void scan3b_kernel(
    int* __restrict__ offs, const int* __restrict__ bsum, int* __restrict__ cursor)
{
    __shared__ int red[128];
    int tid = threadIdx.x;
    if (tid < 128) red[tid] = (tid < (int)blockIdx.x && tid < NB_SCAN) ? bsum[tid] : 0;
    __syncthreads();
    if (tid < 64) red[tid] += red[tid + 64];
    __syncthreads();
    if (tid < 32) red[tid] += red[tid + 32];
    __syncthreads();
    if (tid < 16) red[tid] += red[tid + 16];
    __syncthreads();
    if (tid < 8)  red[tid] += red[tid + 8];
    __syncthreads();
    if (tid < 4)  red[tid] += red[tid + 4];
    __syncthreads();
    if (tid < 2)  red[tid] += red[tid + 2];
    __syncthreads();
    if (tid == 0) red[0] += red[1];
    __syncthreads();
    int base = red[0];
    int gid = blockIdx.x * 1024 + tid;
    if (gid < N_NODES) {
        int v = offs[gid] + base;
        offs[gid] = v;
        cursor[gid] = v;
    }
    if (gid == N_NODES) offs[N_NODES] = N_EDGES;
}

// ===========================================================================
// dense1_lin: u(bf16) = x @ W1l^T ; hv(f32) = x @ W1r^T + b1.
// ===========================================================================
__global__ __launch_bounds__(256) void dense1_lin_kernel(
    const float* __restrict__ x, const float* __restrict__ W1l,
    const float* __restrict__ W1r, const float* __restrict__ b1,
    unsigned short* __restrict__ u, float* __restrict__ hv)
{
    __shared__ float wlT[64 * 65];
    __shared__ float wrT[64 * 65];
    for (int idx = threadIdx.x; idx < 4096; idx += 256) {
        int f = idx >> 6, k = idx & 63;
        wlT[k * 65 + f] = W1l[idx];
        wrT[k * 65 + f] = W1r[idx];
    }
    __syncthreads();

    int f  = threadIdx.x & 63;
    int wv = threadIdx.x >> 6;
    float wl[64], wr[64];
#pragma unroll
    for (int k = 0; k < 64; ++k) {
        wl[k] = wlT[k * 65 + f];
        wr[k] = wrT[k * 65 + f];
    }
    float bias = b1[f];
    int node0 = blockIdx.x * 64;

    for (int nn = 0; nn < 16; ++nn) {
        int node = node0 + nn * 4 + wv;          // wave-uniform
        if (node < N_NODES) {
            float xv = x[(size_t)node * 64 + f];
            float ua = 0.f, va = bias;
#pragma unroll
            for (int k = 0; k < 64; ++k) {
                float xb = bcast(xv, k);
                ua += xb * wl[k];
                va += xb * wr[k];
            }
            u[(size_t)node * 64 + f]  = f2bf(ua);
            hv[(size_t)node * 64 + f] = va;
        }
    }
}

// ===========================================================================
// gather1_bn v5 = v3 (proven 112us half-wave-pair gather, UNCHANGED) + id
// prefetch graft: offs for the wave's 16 nodes preloaded once (shfl-served),
// node nn+1's neighbor ids loaded during node nn's gather rounds -> the
// dependent nbr load leaves the per-node critical path.
// ===========================================================================
__global__ __launch_bounds__(256) void gather1_bn_kernel(
    const unsigned int* __restrict__ u32, const int* __restrict__ offs,
    const int* __restrict__ nbr, float* __restrict__ hv,
    float* __restrict__ sums, float* __restrict__ sumsq)
{
    int lane = threadIdx.x & 63;
    int m    = lane & 31;
    int half = lane >> 5;
    int wv   = threadIdx.x >> 6;
    int node0 = blockIdx.x * 64;

    // offs for nodes node0+4k+wv and their +1, k=0..15, in 32 lanes
    int oidx = node0 + wv + (lane >> 1) * 4 + (lane & 1);
    int ov = offs[min(oidx, N_NODES)];

    int beg_c = __shfl(ov, 0), end_c = __shfl(ov, 1);
    int safe0 = min(max(end_c - 1, beg_c), N_EDGES - 1);
    int id_pref = nbr[min(beg_c + lane, safe0)];

    float s1_0 = 0.f, s1_1 = 0.f, s2_0 = 0.f, s2_1 = 0.f;

    for (int nn = 0; nn < 16; ++nn) {
        int beg = beg_c, end = end_c;
        int id  = id_pref;
        if (nn < 15) {                       // prefetch next node's ids
            beg_c = __shfl(ov, 2 * nn + 2);
            end_c = __shfl(ov, 2 * nn + 3);
            int safe = min(max(end_c - 1, beg_c), N_EDGES - 1);
            id_pref = nbr[min(beg_c + lane, safe)];
        }
        int node = node0 + nn * 4 + wv;
        if (node < N_NODES) {                // wave-uniform
            int deg = end - beg;
            float p0=0,p1=0,p2=0,p3=0,q0=0,q1=0,q2=0,q3=0;
            for (int c = 0; c < deg; c += 64) {
                if (c > 0) {                 // rare: deg > 64
                    int idxl = beg + c + lane;
                    id = nbr[(idxl < end) ? idxl : (end - 1)];
                }
                int cnt = min(deg - c, 64);
                for (int r = 0; r < cnt; r += 16) {   // wave-uniform trips
#pragma unroll
                    for (int i = 0; i < 8; ++i) {
                        int e   = r + 2 * i + half;   // < 64 always
                        int ide = __shfl(id, e);      // id from registers
                        unsigned int w = u32[(size_t)ide * 32 + m];
                        bool val = (e < cnt);
                        float lo = val ? bf16lo(w) : 0.f;
                        float hi = val ? bf16hi(w) : 0.f;
                        if ((i & 3) == 0)      { p0 += lo; q0 += hi; }
                        else if ((i & 3) == 1) { p1 += lo; q1 += hi; }
                        else if ((i & 3) == 2) { p2 += lo; q2 += hi; }
                        else                   { p3 += lo; q3 += hi; }
                    }
                }
            }
            float P = (p0 + p1) + (p2 + p3);
            float Q = (q0 + q1) + (q2 + q3);
            P += __shfl_xor(P, 32);    // combine the two half-waves
            Q += __shfl_xor(Q, 32);
            if (half == 0) {
                float inv = 1.0f / (float)max(deg, 1);
                float2 v = ((const float2*)hv)[(size_t)node * 32 + m];
                float h0 = P * inv + v.x;
                float h1 = Q * inv + v.y;
                ((float2*)hv)[(size_t)node * 32 + m] = make_float2(h0, h1);
                s1_0 += h0; s1_1 += h1;
                s2_0 += h0 * h0; s2_1 += h1 * h1;
            }
        }
    }

    __shared__ float2 redA[256];
    __shared__ float2 redB[256];
    redA[threadIdx.x] = make_float2(s1_0, s1_1);
    redB[threadIdx.x] = make_float2(s2_0, s2_1);
    __syncthreads();
    if (threadIdx.x < 32) {
        int mm = threadIdx.x;
        float a0=0,a1=0,b0=0,b1=0;
        for (int w = 0; w < 4; ++w) {
            float2 A = redA[w * 64 + mm]; a0 += A.x; a1 += A.y;
            float2 B = redB[w * 64 + mm]; b0 += B.x; b1 += B.y;
        }
        atomicAdd(&sums[2 * mm], a0);  atomicAdd(&sums[2 * mm + 1], a1);
        atomicAdd(&sumsq[2 * mm], b0); atomicAdd(&sumsq[2 * mm + 1], b1);
    }
}

// ===========================================================================
// dense2_bn: BN finalize folded in (redundant per block, ~10 insts), then
// BN+ReLU per lane, tmp(bf16, 40/row) = hn @ W2l^T, out = hn @ W2r^T + b2.
// ===========================================================================
__global__ __launch_bounds__(256) void dense2_bn_kernel(
    const float* __restrict__ h, const float* __restrict__ sums,
    const float* __restrict__ sumsq, const float* __restrict__ gamma,
    const float* __restrict__ beta, const float* __restrict__ W2l,
    const float* __restrict__ W2r, const float* __restrict__ b2,
    unsigned short* __restrict__ tmp, float* __restrict__ out)
{
    __shared__ float wlT[64 * 65];
    __shared__ float wrT[64 * 65];
    for (int idx = threadIdx.x; idx < 2560; idx += 256) {
        int f = idx >> 6, k = idx & 63;      // f < 40
        wlT[k * 65 + f] = W2l[idx];
        wrT[k * 65 + f] = W2r[idx];
    }
    __syncthreads();

    int f  = threadIdx.x & 63;
    int wv = threadIdx.x >> 6;
    int fc = (f < 40) ? f : 39;
    float wl[64], wr[64];
#pragma unroll
    for (int k = 0; k < 64; ++k) {
        wl[k] = wlT[k * 65 + fc];
        wr[k] = wrT[k * 65 + fc];
    }
    float bias = b2[fc];

    // BN finalize (was its own kernel): scale/shift from global stats
    float inv_n = 1.0f / (float)N_NODES;
    float mu  = sums[f] * inv_n;
    float var = sumsq[f] * inv_n - mu * mu;
    float rs  = rsqrtf(var + BN_EPS);
    float sc  = gamma[f] * rs;
    float sh  = beta[f] - mu * sc;

    int node0 = blockIdx.x * 64;

    for (int nn = 0; nn < 16; ++nn) {
        int node = node0 + nn * 4 + wv;          // wave-uniform
        if (node < N_NODES) {
            float hvv = h[(size_t)node * 64 + f];
            float hn  = fmaxf(hvv * sc + sh, 0.f);   // BN + ReLU fused
            float ta = 0.f, ra = bias;
#pragma unroll
            for (int k = 0; k < 64; ++k) {
                float hb = bcast(hn, k);
                ta += hb * wl[k];
                ra += hb * wr[k];
            }
            if (f < 40) {
                tmp[(size_t)node * 40 + f] = f2bf(ta);
                out[(size_t)node * 40 + f] = ra;
            }
        }
    }
}

// ===========================================================================
// gather2 v5 = v3 + id-prefetch graft; tmp bf16 stride 20 dwords (80B rows).
// ===========================================================================
__global__ __launch_bounds__(256) void gather2_kernel(
    const unsigned int* __restrict__ t32, const int* __restrict__ offs,
    const int* __restrict__ nbr, float* __restrict__ out)
{
    int lane = threadIdx.x & 63;
    int m    = lane & 31;
    int half = lane >> 5;
    bool act = (m < 20);
    int wv   = threadIdx.x >> 6;
    int node0 = blockIdx.x * 64;

    int oidx = node0 + wv + (lane >> 1) * 4 + (lane & 1);
    int ov = offs[min(oidx, N_NODES)];

    int beg_c = __shfl(ov, 0), end_c = __shfl(ov, 1);
    int safe0 = min(max(end_c - 1, beg_c), N_EDGES - 1);
    int id_pref = nbr[min(beg_c + lane, safe0)];

    for (int nn = 0; nn < 16; ++nn) {
        int beg = beg_c, end = end_c;
        int id  = id_pref;
        if (nn < 15) {
            beg_c = __shfl(ov, 2 * nn + 2);
            end_c = __shfl(ov, 2 * nn + 3);
            int safe = min(max(end_c - 1, beg_c), N_EDGES - 1);
            id_pref = nbr[min(beg_c + lane, safe)];
        }
        int node = node0 + nn * 4 + wv;
        if (node < N_NODES) {                    // wave-uniform
            int deg = end - beg;
            float p0=0,p1=0,p2=0,p3=0,q0=0,q1=0,q2=0,q3=0;
            for (int c = 0; c < deg; c += 64) {
                if (c > 0) {
                    int idxl = beg + c + lane;
                    id = nbr[(idxl < end) ? idxl : (end - 1)];
                }
                int cnt = min(deg - c, 64);
                for (int r = 0; r < cnt; r += 16) {
#pragma unroll
                    for (int i = 0; i < 8; ++i) {
                        int e   = r + 2 * i + half;
                        int ide = __shfl(id, e);     // all lanes execute
                        if (act) {
                            unsigned int w = t32[(size_t)ide * 20 + m];
                            bool val = (e < cnt);
                            float lo = val ? bf16lo(w) : 0.f;
                            float hi = val ? bf16hi(w) : 0.f;
                            if ((i & 3) == 0)      { p0 += lo; q0 += hi; }
                            else if ((i & 3) == 1) { p1 += lo; q1 += hi; }
                            else if ((i & 3) == 2) { p2 += lo; q2 += hi; }
                            else                   { p3 += lo; q3 += hi; }
                        }
                    }
                }
            }
            float P = (p0 + p1) + (p2 + p3);
            float Q = (q0 + q1) + (q2 + q3);
            P += __shfl_xor(P, 32);
            Q += __shfl_xor(Q, 32);
            if (half == 0 && act) {
                float inv = 1.0f / (float)max(deg, 1);
                float2 o = ((float2*)out)[(size_t)node * 20 + m];
                o.x += P * inv;
                o.y += Q * inv;
                ((float2*)out)[(size_t)node * 20 + m] = o;
            }
        }
    }
}

extern "C" void kernel_launch(void* const* d_in, const int* in_sizes, int n_in,
                              void* d_out, int out_size, void* d_ws, size_t ws_size,
                              hipStream_t stream)
{
    const float* x     = (const float*)d_in[0];
    const int*   ei    = (const int*)d_in[1];
    const float* W1l   = (const float*)d_in[2];
    const float* W1r   = (const float*)d_in[3];
    const float* b1    = (const float*)d_in[4];
    const float* gamma = (const float*)d_in[5];
    const float* beta  = (const float*)d_in[6];
    const float* W2l   = (const float*)d_in[7];
    const float* W2r   = (const float*)d_in[8];
    const float* b2    = (const float*)d_in[9];
    float* out = (float*)d_out;

    const int* src = ei;
    const int* dst = ei + N_EDGES;

    // workspace layout (~46 MB; 58.8 MB available). sums..deg contiguous so
    // ONE memset zeroes BN stats + degree histogram.
    float* ws    = (float*)d_ws;
    float* hv    = ws;                               // f32 [N*64]
    float* sums  = hv + (size_t)N_NODES * 64;        // 64
    float* sumsq = sums + 64;                        // 64
    float* scale = sumsq + 64;                       // 64 (unused slot, kept)
    float* shift = scale + 64;                       // 64
    int* deg    = (int*)(shift + 64);                // N  <- zeroed with sums
    int* offs   = deg + N_NODES;                     // N+1
    int* cursor = offs + N_NODES + 1;                // N
    int* bsum   = cursor + N_NODES;                  // 128
    unsigned short* u = (unsigned short*)(bsum + 128);   // bf16 [N*64]
    unsigned short* tmpb = u;                        // bf16 [N*40], reuses u
    int* nbr    = (int*)(u + (size_t)N_NODES * 64);  // E
    (void)scale; (void)shift;

    dim3 blk(256);

    // ---- CSR build (XCD-partitioned) + BN-stat zeroing: 1 memset ----
    hipMemsetAsync(sums, 0, (size_t)(256 + N_NODES) * sizeof(int), stream);
    histogram_xcd_kernel<<<FILL_CHUNKS * 8, blk, 0, stream>>>(dst, deg);
    scan1_kernel<<<NB_SCAN, 1024, 0, stream>>>(deg, offs, bsum);
    scan3b_kernel<<<NB_SCAN, 1024, 0, stream>>>(offs, bsum, cursor);
    fill_xcd_kernel<<<FILL_CHUNKS * 8, blk, 0, stream>>>(src, dst, cursor, nbr);

    int dblocks = (N_NODES + 63) / 64;
    int gblocks = (N_NODES + 63) / 64;

    // ---- layer 1 ----
    dense1_lin_kernel<<<dblocks, blk, 0, stream>>>(x, W1l, W1r, b1, u, hv);
    gather1_bn_kernel<<<gblocks, blk, 0, stream>>>(
        (const unsigned int*)u, offs, nbr, hv, sums, sumsq);

    // ---- layer 2 (BN finalize + BN+ReLU fused into dense2) ----
    dense2_bn_kernel<<<dblocks, blk, 0, stream>>>(
        hv, sums, sumsq, gamma, beta, W2l, W2r, b2, tmpb, out);
    gather2_kernel<<<gblocks, blk, 0, stream>>>(
        (const unsigned int*)tmpb, offs, nbr, out);
}

// Round 12
// 509.587 us; speedup vs baseline: 1.0881x; 1.0881x over previous
//
#include <hip/hip_runtime.h>

#define N_NODES 100000
#define N_EDGES 1600000
#define BN_EPS 1e-5f
#define NB_SCAN 98       // ceil(100000/1024)
#define PART_SZ 12500    // N_NODES / 8 XCD partitions
#define FILL_CHUNKS 1024
#define CHUNK_SZ 1563    // ceil(N_EDGES / FILL_CHUNKS)

// broadcast lane k's value (readlane). Wave-uniform control flow ONLY.
__device__ __forceinline__ float bcast(float v, int k) {
    return __uint_as_float(__builtin_amdgcn_readlane(__float_as_uint(v), k));
}
__device__ __forceinline__ float bf16lo(unsigned int w) {
    return __uint_as_float(w << 16);
}
__device__ __forceinline__ float bf16hi(unsigned int w) {
    return __uint_as_float(w & 0xFFFF0000u);
}
__device__ __forceinline__ unsigned short f2bf(float x) {   // round-nearest-even
    unsigned int u = __float_as_uint(x);
    return (unsigned short)((u + 0x7FFF + ((u >> 16) & 1)) >> 16);
}

// ===========================================================================
// CSR build, XCD-partitioned (R10, proven): grid = FILL_CHUNKS x 8; block b
// scans chunk b>>3, keeps dst in partition (b&7) -> per-XCD L2 owns its
// 1/8 slice of deg/cursor/nbr; scattered stores merge in-L2.
// ===========================================================================
__global__ __launch_bounds__(256) void histogram_xcd_kernel(
    const int* __restrict__ dst, int* __restrict__ deg)
{
    int part  = blockIdx.x & 7;
    int lo = part * PART_SZ, hi = lo + PART_SZ;
    int base  = (blockIdx.x >> 3) * CHUNK_SZ;
    int endE  = min(base + CHUNK_SZ, N_EDGES);
    for (int e = base + threadIdx.x; e < endE; e += 256) {
        int d = dst[e];
        if (d >= lo && d < hi) atomicAdd(&deg[d], 1);
    }
}

__global__ __launch_bounds__(256) void fill_xcd_kernel(
    const int* __restrict__ src, const int* __restrict__ dst,
    int* __restrict__ cursor, int* __restrict__ nbr)
{
    int part  = blockIdx.x & 7;
    int lo = part * PART_SZ, hi = lo + PART_SZ;
    int base  = (blockIdx.x >> 3) * CHUNK_SZ;
    int endE  = min(base + CHUNK_SZ, N_EDGES);
    for (int e = base + threadIdx.x; e < endE; e += 256) {
        int d = dst[e];
        if (d >= lo && d < hi) {
            int p = atomicAdd(&cursor[d], 1);
            nbr[p] = src[e];
        }
    }
}

__global__ __launch_bounds__(1024) void scan1_kernel(
    const int* __restrict__ deg, int* __restrict__ offs, int* __restrict__ bsum)
{
    __shared__ int tmp[1024];
    int gid = blockIdx.x * 1024 + threadIdx.x;
    int v = (gid < N_NODES) ? deg[gid] : 0;
    tmp[threadIdx.x] = v;
    __syncthreads();
    for (int off = 1; off < 1024; off <<= 1) {
        int t = (threadIdx.x >= off) ? tmp[threadIdx.x - off] : 0;
        __syncthreads();
        tmp[threadIdx.x] += t;
        __syncthreads();
    }
    if (gid < N_NODES) offs[gid] = tmp[threadIdx.x] - v;
    if (threadIdx.x == 1023) bsum[blockIdx.x] = tmp[1023];
}

// scan3b: replaces scan2+scan3 — each block redundantly reduces bsum.
__global__ __launch_bounds__(1024) void scan3b_kernel(
    int* __restrict__ offs, const int* __restrict__ bsum, int* __restrict__ cursor)
{
    __shared__ int red[128];
    int tid = threadIdx.x;
    if (tid < 128) red[tid] = (tid < (int)blockIdx.x && tid < NB_SCAN) ? bsum[tid] : 0;
    __syncthreads();
    if (tid < 64) red[tid] += red[tid + 64];
    __syncthreads();
    if (tid < 32) red[tid] += red[tid + 32];
    __syncthreads();
    if (tid < 16) red[tid] += red[tid + 16];
    __syncthreads();
    if (tid < 8)  red[tid] += red[tid + 8];
    __syncthreads();
    if (tid < 4)  red[tid] += red[tid + 4];
    __syncthreads();
    if (tid < 2)  red[tid] += red[tid + 2];
    __syncthreads();
    if (tid == 0) red[0] += red[1];
    __syncthreads();
    int base = red[0];
    int gid = blockIdx.x * 1024 + tid;
    if (gid < N_NODES) {
        int v = offs[gid] + base;
        offs[gid] = v;
        cursor[gid] = v;
    }
    if (gid == N_NODES) offs[N_NODES] = N_EDGES;
}

// ===========================================================================
// dense1_lin: u(bf16) = x @ W1l^T ; hv(f32) = x @ W1r^T + b1.
// ===========================================================================
__global__ __launch_bounds__(256) void dense1_lin_kernel(
    const float* __restrict__ x, const float* __restrict__ W1l,
    const float* __restrict__ W1r, const float* __restrict__ b1,
    unsigned short* __restrict__ u, float* __restrict__ hv)
{
    __shared__ float wlT[64 * 65];
    __shared__ float wrT[64 * 65];
    for (int idx = threadIdx.x; idx < 4096; idx += 256) {
        int f = idx >> 6, k = idx & 63;
        wlT[k * 65 + f] = W1l[idx];
        wrT[k * 65 + f] = W1r[idx];
    }
    __syncthreads();

    int f  = threadIdx.x & 63;
    int wv = threadIdx.x >> 6;
    float wl[64], wr[64];
#pragma unroll
    for (int k = 0; k < 64; ++k) {
        wl[k] = wlT[k * 65 + f];
        wr[k] = wrT[k * 65 + f];
    }
    float bias = b1[f];
    int node0 = blockIdx.x * 64;

    for (int nn = 0; nn < 16; ++nn) {
        int node = node0 + nn * 4 + wv;          // wave-uniform
        if (node < N_NODES) {
            float xv = x[(size_t)node * 64 + f];
            float ua = 0.f, va = bias;
#pragma unroll
            for (int k = 0; k < 64; ++k) {
                float xb = bcast(xv, k);
                ua += xb * wl[k];
                va += xb * wr[k];
            }
            u[(size_t)node * 64 + f]  = f2bf(ua);
            hv[(size_t)node * 64 + f] = va;
        }
    }
}

// ===========================================================================
// gather1_bn v3 (EXACT R10 revert, proven 112 us): per 64-edge chunk ONE
// coalesced id load; ids via __shfl; half-wave edge pairs; 16 nodes/wave.
// (R11's id-prefetch graft REGRESSED: FETCH 91->160 MB. Do not re-add.)
// ===========================================================================
__global__ __launch_bounds__(256) void gather1_bn_kernel(
    const unsigned int* __restrict__ u32, const int* __restrict__ offs,
    const int* __restrict__ nbr, float* __restrict__ hv,
    float* __restrict__ sums, float* __restrict__ sumsq)
{
    int lane = threadIdx.x & 63;
    int m    = lane & 31;
    int half = lane >> 5;
    int wv   = threadIdx.x >> 6;
    int node0 = blockIdx.x * 64;
    float s1_0 = 0.f, s1_1 = 0.f, s2_0 = 0.f, s2_1 = 0.f;

    for (int nn = 0; nn < 16; ++nn) {
        int node = node0 + nn * 4 + wv;
        if (node < N_NODES) {                    // wave-uniform
            int beg = offs[node], end = offs[node + 1];
            int deg = end - beg;
            float p0=0,p1=0,p2=0,p3=0,q0=0,q1=0,q2=0,q3=0;
            for (int c = 0; c < deg; c += 64) {  // ~always 1 iteration
                int idx = beg + c + lane;
                int id  = nbr[(idx < end) ? idx : (end - 1)];  // coalesced
                int cnt = min(deg - c, 64);
                for (int r = 0; r < cnt; r += 16) {   // wave-uniform trips
#pragma unroll
                    for (int i = 0; i < 8; ++i) {
                        int e   = r + 2 * i + half;   // < 64 always
                        int ide = __shfl(id, e);      // id from registers
                        unsigned int w = u32[(size_t)ide * 32 + m];
                        bool val = (e < cnt);
                        float lo = val ? bf16lo(w) : 0.f;
                        float hi = val ? bf16hi(w) : 0.f;
                        if ((i & 3) == 0)      { p0 += lo; q0 += hi; }
                        else if ((i & 3) == 1) { p1 += lo; q1 += hi; }
                        else if ((i & 3) == 2) { p2 += lo; q2 += hi; }
                        else                   { p3 += lo; q3 += hi; }
                    }
                }
            }
            float P = (p0 + p1) + (p2 + p3);
            float Q = (q0 + q1) + (q2 + q3);
            P += __shfl_xor(P, 32);    // combine the two half-waves
            Q += __shfl_xor(Q, 32);
            if (half == 0) {
                float inv = 1.0f / (float)max(deg, 1);
                float2 v = ((const float2*)hv)[(size_t)node * 32 + m];
                float h0 = P * inv + v.x;
                float h1 = Q * inv + v.y;
                ((float2*)hv)[(size_t)node * 32 + m] = make_float2(h0, h1);
                s1_0 += h0; s1_1 += h1;
                s2_0 += h0 * h0; s2_1 += h1 * h1;
            }
        }
    }

    __shared__ float2 redA[256];
    __shared__ float2 redB[256];
    redA[threadIdx.x] = make_float2(s1_0, s1_1);
    redB[threadIdx.x] = make_float2(s2_0, s2_1);
    __syncthreads();
    if (threadIdx.x < 32) {
        int mm = threadIdx.x;
        float a0=0,a1=0,b0=0,b1=0;
        for (int w = 0; w < 4; ++w) {
            float2 A = redA[w * 64 + mm]; a0 += A.x; a1 += A.y;
            float2 B = redB[w * 64 + mm]; b0 += B.x; b1 += B.y;
        }
        atomicAdd(&sums[2 * mm], a0);  atomicAdd(&sums[2 * mm + 1], a1);
        atomicAdd(&sumsq[2 * mm], b0); atomicAdd(&sumsq[2 * mm + 1], b1);
    }
}

// ===========================================================================
// dense2_bn: BN finalize folded in; BN+ReLU per lane; projections split:
// tmp32 (32 bf16 = 64B rows) + tmp8 (8 bf16 = 16B rows) for the gather;
// out = hn @ W2r^T + b2 written directly.
// ===========================================================================
__global__ __launch_bounds__(256) void dense2_bn_kernel(
    const float* __restrict__ h, const float* __restrict__ sums,
    const float* __restrict__ sumsq, const float* __restrict__ gamma,
    const float* __restrict__ beta, const float* __restrict__ W2l,
    const float* __restrict__ W2r, const float* __restrict__ b2,
    unsigned short* __restrict__ tmp32, unsigned short* __restrict__ tmp8,
    float* __restrict__ out)
{
    __shared__ float wlT[64 * 65];
    __shared__ float wrT[64 * 65];
    for (int idx = threadIdx.x; idx < 2560; idx += 256) {
        int f = idx >> 6, k = idx & 63;      // f < 40
        wlT[k * 65 + f] = W2l[idx];
        wrT[k * 65 + f] = W2r[idx];
    }
    __syncthreads();

    int f  = threadIdx.x & 63;
    int wv = threadIdx.x >> 6;
    int fc = (f < 40) ? f : 39;
    float wl[64], wr[64];
#pragma unroll
    for (int k = 0; k < 64; ++k) {
        wl[k] = wlT[k * 65 + fc];
        wr[k] = wrT[k * 65 + fc];
    }
    float bias = b2[fc];

    // BN finalize (redundant per block, ~10 insts)
    float inv_n = 1.0f / (float)N_NODES;
    float mu  = sums[f] * inv_n;
    float var = sumsq[f] * inv_n - mu * mu;
    float rs  = rsqrtf(var + BN_EPS);
    float sc  = gamma[f] * rs;
    float sh  = beta[f] - mu * sc;

    int node0 = blockIdx.x * 64;

    for (int nn = 0; nn < 16; ++nn) {
        int node = node0 + nn * 4 + wv;          // wave-uniform
        if (node < N_NODES) {
            float hvv = h[(size_t)node * 64 + f];
            float hn  = fmaxf(hvv * sc + sh, 0.f);   // BN + ReLU fused
            float ta = 0.f, ra = bias;
#pragma unroll
            for (int k = 0; k < 64; ++k) {
                float hb = bcast(hn, k);
                ta += hb * wl[k];
                ra += hb * wr[k];
            }
            if (f < 32) {
                tmp32[(size_t)node * 32 + f] = f2bf(ta);
            } else if (f < 40) {
                tmp8[(size_t)node * 8 + (f - 32)] = f2bf(ta);
            }
            if (f < 40) out[(size_t)node * 40 + f] = ra;
        }
    }
}

// ===========================================================================
// gather2 v6: out += mean over neighbors of [tmp32 | tmp8].
// tmp32: 64B rows -> quarter-wave, 4 edges per dword instr, 1 line/edge
//        (halves expensive random line-touches vs the 80B-row layout).
// tmp8:  16B rows, 4 nodes/line, 1.6MB total -> L2-resident, 16 edges per
//        instr (4 lanes each) -> near-free.
// Rounds stay 16-edge (deg-matched, the v3 lesson); ids via __shfl.
// ===========================================================================
__global__ __launch_bounds__(256) void gather2_kernel(
    const unsigned int* __restrict__ t32, const unsigned int* __restrict__ t8,
    const int* __restrict__ offs, const int* __restrict__ nbr,
    float* __restrict__ out)
{
    int lane = threadIdx.x & 63;
    int q    = lane >> 4;       // quarter 0..3
    int m    = lane & 15;       // dword in 64B row (feats 2m, 2m+1)
    int j    = lane & 3;        // dword in 16B row (feats 32+2j, 33+2j)
    int g    = lane >> 2;       // edge-group for tmp8 (0..15)
    int wv   = threadIdx.x >> 6;
    int node0 = blockIdx.x * 64;

    for (int nn = 0; nn < 16; ++nn) {
        int node = node0 + nn * 4 + wv;
        if (node < N_NODES) {                    // wave-uniform
            int beg = offs[node], end = offs[node + 1];
            int deg = end - beg;
            float p0=0,p1=0,p2=0,p3=0;           // tmp32 partials
            float e8a=0, e8b=0;                  // tmp8 partials
            for (int c = 0; c < deg; c += 64) {
                int idx = beg + c + lane;
                int id  = nbr[(idx < end) ? idx : (end - 1)];  // coalesced
                int cnt = min(deg - c, 64);
                for (int r = 0; r < cnt; r += 16) {
#pragma unroll
                    for (int i = 0; i < 4; ++i) {           // tmp32: 4x4 edges
                        int e   = r + 4 * i + q;
                        int ide = __shfl(id, min(e, cnt - 1));
                        unsigned int w = t32[(size_t)ide * 16 + m];
                        bool val = (e < cnt);
                        float lo = val ? bf16lo(w) : 0.f;
                        float hi = val ? bf16hi(w) : 0.f;
                        if (i & 1) { p2 += lo; p3 += hi; }
                        else       { p0 += lo; p1 += hi; }
                    }
                    {                                        // tmp8: 16 edges
                        int e   = r + g;
                        int ide = __shfl(id, min(e, cnt - 1));
                        unsigned int w = t8[(size_t)ide * 4 + j];
                        bool val = (e < cnt);
                        e8a += val ? bf16lo(w) : 0.f;
                        e8b += val ? bf16hi(w) : 0.f;
                    }
                }
            }
            // tmp32: sum quarters -> lanes 0..15 hold feats 2m, 2m+1
            float P0 = p0 + p2, P1 = p1 + p3;
            P0 += __shfl_xor(P0, 16); P0 += __shfl_xor(P0, 32);
            P1 += __shfl_xor(P1, 16); P1 += __shfl_xor(P1, 32);
            // tmp8: sum the 16 edge-groups (lanes sharing j) -> every lane
            // holds the total for its j
            e8a += __shfl_xor(e8a, 4);  e8a += __shfl_xor(e8a, 8);
            e8a += __shfl_xor(e8a, 16); e8a += __shfl_xor(e8a, 32);
            e8b += __shfl_xor(e8b, 4);  e8b += __shfl_xor(e8b, 8);
            e8b += __shfl_xor(e8b, 16); e8b += __shfl_xor(e8b, 32);
            float inv = 1.0f / (float)max(deg, 1);
            if (lane < 16) {
                float2 o = ((float2*)out)[(size_t)node * 20 + m];
                o.x += P0 * inv;
                o.y += P1 * inv;
                ((float2*)out)[(size_t)node * 20 + m] = o;
            } else if (lane < 20) {      // lanes 16..19 have j=0..3 totals
                float2 o = ((float2*)out)[(size_t)node * 20 + 16 + j];
                o.x += e8a * inv;
                o.y += e8b * inv;
                ((float2*)out)[(size_t)node * 20 + 16 + j] = o;
            }
        }
    }
}

extern "C" void kernel_launch(void* const* d_in, const int* in_sizes, int n_in,
                              void* d_out, int out_size, void* d_ws, size_t ws_size,
                              hipStream_t stream)
{
    const float* x     = (const float*)d_in[0];
    const int*   ei    = (const int*)d_in[1];
    const float* W1l   = (const float*)d_in[2];
    const float* W1r   = (const float*)d_in[3];
    const float* b1    = (const float*)d_in[4];
    const float* gamma = (const float*)d_in[5];
    const float* beta  = (const float*)d_in[6];
    const float* W2l   = (const float*)d_in[7];
    const float* W2r   = (const float*)d_in[8];
    const float* b2    = (const float*)d_in[9];
    float* out = (float*)d_out;

    const int* src = ei;
    const int* dst = ei + N_EDGES;

    // workspace layout (~46 MB; 58.8 MB available). All arrays 64B-aligned
    // (offs padded to N+16). sums..deg contiguous -> one memset.
    float* ws    = (float*)d_ws;
    float* hv    = ws;                               // f32 [N*64]
    float* sums  = hv + (size_t)N_NODES * 64;        // 64
    float* sumsq = sums + 64;                        // 64
    float* padf  = sumsq + 64;                       // 128 pad (keeps 64B align)
    int* deg    = (int*)(padf + 128);                // N
    int* offs   = deg + N_NODES;                     // N+16 (padded)
    int* cursor = offs + N_NODES + 16;               // N
    int* bsum   = cursor + N_NODES;                  // 128
    unsigned short* u = (unsigned short*)(bsum + 128);   // bf16 [N*64], 64B-aligned
    unsigned short* t32v = u;                        // bf16 [N*32], reuses u
    unsigned short* t8v  = u + (size_t)N_NODES * 32; // bf16 [N*8]
    int* nbr    = (int*)(u + (size_t)N_NODES * 64);  // E

    dim3 blk(256);

    // ---- CSR build (XCD-partitioned) + BN-stat zeroing: 1 memset ----
    hipMemsetAsync(sums, 0, (size_t)(256 + N_NODES) * sizeof(int), stream);
    histogram_xcd_kernel<<<FILL_CHUNKS * 8, blk, 0, stream>>>(dst, deg);
    scan1_kernel<<<NB_SCAN, 1024, 0, stream>>>(deg, offs, bsum);
    scan3b_kernel<<<NB_SCAN, 1024, 0, stream>>>(offs, bsum, cursor);
    fill_xcd_kernel<<<FILL_CHUNKS * 8, blk, 0, stream>>>(src, dst, cursor, nbr);

    int dblocks = (N_NODES + 63) / 64;
    int gblocks = (N_NODES + 63) / 64;

    // ---- layer 1 ----
    dense1_lin_kernel<<<dblocks, blk, 0, stream>>>(x, W1l, W1r, b1, u, hv);
    gather1_bn_kernel<<<gblocks, blk, 0, stream>>>(
        (const unsigned int*)u, offs, nbr, hv, sums, sumsq);

    // ---- layer 2 (BN finalize + BN+ReLU fused into dense2) ----
    dense2_bn_kernel<<<dblocks, blk, 0, stream>>>(
        hv, sums, sumsq, gamma, beta, W2l, W2r, b2, t32v, t8v, out);
    gather2_kernel<<<gblocks, blk, 0, stream>>>(
        (const unsigned int*)t32v, (const unsigned int*)t8v, offs, nbr, out);
}